// Round 3
// baseline (139.089 us; speedup 1.0000x reference)
//
#include <hip/hip_runtime.h>
#include <math.h>

#define W_ 128
#define H_ 96
#define HW_ (H_ * W_)          // 12288
#define K_ 81
#define FLOW_ELEMS (2 * 2 * H_ * W_)   // 49152
#define HALO_W 136             // cols -4..131
#define HALO_H 9               // dy -4..4
#define NSLOT 1224             // 4 ch * 9 rows * 34 quads
#define NITER 16               // 64 ch per block / 4 staged per iter
#define ACC_STRIDE 84

union SmemU {
    float buf[2][4][HALO_H][HALO_W];   // 39168 B (stage phase)
    float accbuf[W_][ACC_STRIDE];      // 43008 B (reduce phase)
};

// Block = 384 thr = 6 waves = 2 cgroups (32ch each) x 3 dygroups (3 dy rows).
// Block handles 64 channels (cs half); tile = one image row (128 px);
// lane owns pixels x=2*lane, 2*lane+1.
// Grid = 384 = 8 XCD chunks * 48; XCD chunk = 12 consecutive y * (b,cs).
__global__ __launch_bounds__(384, 4) void corr_kernel(const float* __restrict__ f0,
                                                      const float* __restrict__ f1,
                                                      float* __restrict__ corr0,
                                                      float* __restrict__ corr1,
                                                      int use_ws) {
    __shared__ SmemU sm;

    const int t = threadIdx.x;
    const int wave = t >> 6;
    const int lane = t & 63;
    const int cg = wave & 1;             // channel group within block
    const int dg = wave >> 1;            // dy group: rows dg*3 .. dg*3+2

    // XCD-aware bijective swizzle: hw block i -> xcd i&7 owns logical L chunk
    const int L = (blockIdx.x & 7) * 48 + (blockIdx.x >> 3);
    const int y0 = L >> 2;               // 0..95
    const int b  = (L >> 1) & 1;
    const int cs = L & 1;                // channel half

    // ---- staging slots (4 per thread; 1224 live) ----
    int s_ch[4], s_row[4], s_q[4], s_lds[4];
    bool s_live[4];
#pragma unroll
    for (int i = 0; i < 4; ++i) {
        const int s = t + i * 384;
        s_live[i] = (s < NSLOT);
        const int s2 = s_live[i] ? s : 0;
        s_ch[i] = s2 / (HALO_H * 34);
        const int rem = s2 - s_ch[i] * (HALO_H * 34);
        s_row[i] = rem / 34;
        s_q[i] = rem - s_row[i] * 34;
        s_lds[i] = (s_ch[i] * HALO_H + s_row[i]) * HALO_W + s_q[i] * 4;
    }

    float acc0[27], acc1[27];
#pragma unroll
    for (int k = 0; k < 27; ++k) { acc0[k] = 0.f; acc1[k] = 0.f; }

    const float* f1b = f1 + (size_t)b * 128 * HW_;
    const float* f0b = f0 + (size_t)b * 128 * HW_;
    const int cbase = cs * 64;

    // ---- prologue: stage chunk 0 + f0 for it=0 ----
#pragma unroll
    for (int i = 0; i < 4; ++i) {
        if (s_live[i]) {
            const int c = cbase + (s_ch[i] >> 1) * 32 + (s_ch[i] & 1);
            const int gy = y0 + s_row[i] - 4;
            const int q = s_q[i];
            float4 v = make_float4(0.f, 0.f, 0.f, 0.f);
            if (gy >= 0 && gy < H_ && q >= 1 && q <= 32)
                v = *(const float4*)(f1b + (size_t)c * HW_ + gy * W_ + (q * 4 - 4));
            *(float4*)(&sm.buf[0][0][0][0] + s_lds[i]) = v;
        }
    }
    float2 cf0[2];
#pragma unroll
    for (int sub = 0; sub < 2; ++sub)
        cf0[sub] = *(const float2*)(f0b + (size_t)(cbase + cg * 32 + sub) * HW_ + y0 * W_ + 2 * lane);
    __syncthreads();

    // ---- main loop: 16 chunks x 4 channels (2 per cgroup) ----
    for (int it = 0; it < NITER; ++it) {
        const int p = it & 1;
        const bool do_stage = (it + 1 < NITER);

        // T14: issue next-chunk f1 loads AND next f0 loads now; LDS-write after compute
        float4 vals[4];
        float2 nf0[2];
        if (do_stage) {
            const int nit = it + 1;
#pragma unroll
            for (int i = 0; i < 4; ++i) {
                float4 v = make_float4(0.f, 0.f, 0.f, 0.f);
                if (s_live[i]) {
                    const int c = cbase + (s_ch[i] >> 1) * 32 + nit * 2 + (s_ch[i] & 1);
                    const int gy = y0 + s_row[i] - 4;
                    const int q = s_q[i];
                    if (gy >= 0 && gy < H_ && q >= 1 && q <= 32)
                        v = *(const float4*)(f1b + (size_t)c * HW_ + gy * W_ + (q * 4 - 4));
                }
                vals[i] = v;
            }
#pragma unroll
            for (int sub = 0; sub < 2; ++sub)
                nf0[sub] = *(const float2*)(f0b + (size_t)(cbase + cg * 32 + nit * 2 + sub) * HW_ + y0 * W_ + 2 * lane);
        }

        // compute: channels cbase + cg*32 + it*2 + {0,1}
#pragma unroll
        for (int sub = 0; sub < 2; ++sub) {
            const float2 f0v = cf0[sub];
            const int ch4 = cg * 2 + sub;
#pragma unroll
            for (int dl = 0; dl < 3; ++dl) {
                const int hr = dg * 3 + dl;
                const float2* row = (const float2*)(&sm.buf[p][ch4][hr][0]) + lane;
                const float2 w0 = row[0], w1 = row[1], w2 = row[2], w3 = row[3], w4 = row[4];
                const float v[10] = {w0.x, w0.y, w1.x, w1.y, w2.x,
                                     w2.y, w3.x, w3.y, w4.x, w4.y};
#pragma unroll
                for (int dx = 0; dx < 9; ++dx) {
                    acc0[dl * 9 + dx] += f0v.x * v[dx];
                    acc1[dl * 9 + dx] += f0v.y * v[dx + 1];
                }
            }
        }

        if (do_stage) {
#pragma unroll
            for (int i = 0; i < 4; ++i)
                if (s_live[i]) *(float4*)(&sm.buf[p ^ 1][0][0][0] + s_lds[i]) = vals[i];
            cf0[0] = nf0[0];
            cf0[1] = nf0[1];
        }
        __syncthreads();
    }

    // ---- switch LDS to accbuf: zero, reduce cgroups (2-way atomics) ----
    for (int i = t; i < W_ * ACC_STRIDE; i += 384) (&sm.accbuf[0][0])[i] = 0.f;
    __syncthreads();
#pragma unroll
    for (int dl = 0; dl < 3; ++dl)
#pragma unroll
        for (int dx = 0; dx < 9; ++dx) {
            const int k = (dg * 3 + dl) * 9 + dx;
            atomicAdd(&sm.accbuf[2 * lane][k], acc0[dl * 9 + dx]);
            atomicAdd(&sm.accbuf[2 * lane + 1][k], acc1[dl * 9 + dx]);
        }
    __syncthreads();

    // ---- writeout: flat i == px*81 + k (coalesced) ----
    const size_t base = ((size_t)b * HW_ + (size_t)y0 * W_) * K_;
    if (use_ws) {
        float* dst = (cs ? corr1 : corr0) + base;
        for (int i = t; i < W_ * K_; i += 384) {
            const int px = i / K_;
            dst[i] = sm.accbuf[px][i - px * K_];
        }
    } else {
        float* dst = corr0 + base;
        for (int i = t; i < W_ * K_; i += 384) {
            const int px = i / K_;
            atomicAdd(&dst[i], sm.accbuf[px][i - px * K_]);
        }
    }
}

// Kernel 2: merge partials, scale 1/sqrt(128), softmax over K, prob + flow.
__global__ __launch_bounds__(256) void softmax_kernel(float* __restrict__ out,
                                                      const float* __restrict__ corr1,
                                                      int use_ws) {
    const int t = threadIdx.x;
    const int wave = t >> 6, lane = t & 63;
    const int px = (blockIdx.x << 2) + wave;      // 0 .. 24575
    const int b = px / HW_;
    const int pl = px - b * HW_;
    const int y = pl >> 7, x = pl & 127;

    float* corr = out + FLOW_ELEMS + (size_t)px * K_;
    const float* c1 = corr1 + (size_t)px * K_;
    const float scale = 0.08838834764831845f;     // 1/sqrt(128)

    const bool has1 = lane < (K_ - 64);           // lane < 17
    float v0 = corr[lane];
    float v1 = has1 ? corr[lane + 64] : 0.f;
    if (use_ws) {
        v0 += c1[lane];
        if (has1) v1 += c1[lane + 64];
    }
    v0 *= scale;
    v1 = has1 ? v1 * scale : -1e30f;

    float m = fmaxf(v0, v1);
#pragma unroll
    for (int off = 32; off; off >>= 1) m = fmaxf(m, __shfl_xor(m, off));

    float e0 = __expf(v0 - m);
    float e1 = has1 ? __expf(v1 - m) : 0.f;
    float s = e0 + e1;
#pragma unroll
    for (int off = 32; off; off >>= 1) s += __shfl_xor(s, off);

    const float inv = 1.f / s;
    const float p0 = e0 * inv;
    const float p1 = e1 * inv;

    corr[lane] = p0;
    if (has1) corr[lane + 64] = p1;

    float fx = p0 * (float)(lane % 9 - 4) + p1 * (float)((lane + 64) % 9 - 4);
    float fy = p0 * (float)(lane / 9 - 4) + p1 * (float)((lane + 64) / 9 - 4);
#pragma unroll
    for (int off = 32; off; off >>= 1) {
        fx += __shfl_xor(fx, off);
        fy += __shfl_xor(fy, off);
    }

    if (lane == 0) {
        out[((size_t)(b * 2 + 0) * H_ + y) * W_ + x] = fx;
        out[((size_t)(b * 2 + 1) * H_ + y) * W_ + x] = fy;
    }
}

extern "C" void kernel_launch(void* const* d_in, const int* in_sizes, int n_in,
                              void* d_out, int out_size, void* d_ws, size_t ws_size,
                              hipStream_t stream) {
    (void)in_sizes; (void)n_in; (void)out_size;
    const float* f0 = (const float*)d_in[0];
    const float* f1 = (const float*)d_in[1];
    float* out = (float*)d_out;
    float* corr0 = out + FLOW_ELEMS;

    const size_t PART_BYTES = (size_t)2 * HW_ * K_ * sizeof(float);  // 7.96 MB
    const int use_ws = (ws_size >= PART_BYTES) ? 1 : 0;
    float* corr1 = use_ws ? (float*)d_ws : corr0;

    if (!use_ws)
        hipMemsetAsync(corr0, 0, PART_BYTES, stream);

    corr_kernel<<<384, 384, 0, stream>>>(f0, f1, corr0, corr1, use_ws);
    softmax_kernel<<<6144, 256, 0, stream>>>(out, corr1, use_ws);
}

// Round 5
// 41.591 us; speedup vs baseline: 3.3442x; 3.3442x over previous
//
#include <hip/hip_runtime.h>
#include <math.h>

#define W_ 128
#define H_ 96
#define C_ 128
#define HW_ (H_ * W_)          // 12288
#define K_ 81
#define FLOW_ELEMS (2 * 2 * H_ * W_)   // 49152

// Corr kernel, dy-sliced: one 64-thread block (= one wave) per (b, y0, dg),
// dg in 0..8 -> dy = dg-4. The wave accumulates ALL 128 channels for its single
// halo row r = y0+dg-4 and writes the disjoint k-slice [dg*9, dg*9+9) of corr
// for all 128 pixels of row y0. No cross-wave reduction anywhere.
// Lane owns pixels x = 2*lane, 2*lane+1. Grid = 1728 blocks (8 XCD chunks x 216).
__global__ __launch_bounds__(64) void corr_kernel(const float* __restrict__ f0,
                                                  const float* __restrict__ f1,
                                                  float* __restrict__ corr) {
    __shared__ float lds[8][136];   // 8-channel chunk of the halo row (4352 B)

    const int lane = threadIdx.x;

    // XCD-bijective swizzle: 1728 = 8 * 216
    const int L = (blockIdx.x & 7) * 216 + (blockIdx.x >> 3);
    const int dg = L % 9;
    const int rid = L / 9;               // 0..191
    const int y0 = rid % H_;
    const int b  = rid / H_;
    const int r  = y0 + dg - 4;          // halo row in f1 (may be OOB)
    const bool rok = (r >= 0) && (r < H_);

    // staging: lane q stages quad q covering f1 columns q*4-4 .. q*4-1;
    // LDS word w holds column w-4. Quads 0 and 33 are fully OOB -> zeros.
    const int q = lane;
    const bool qok = rok && (q >= 1) && (q <= 32);
    const float* f0p = f0 + (size_t)b * C_ * HW_ + (size_t)y0 * W_ + 2 * lane;
    const float* f1p = f1 + (size_t)b * C_ * HW_ + (size_t)(rok ? r : 0) * W_ + (q * 4 - 4);

    float acc0[9], acc1[9];
#pragma unroll
    for (int j = 0; j < 9; ++j) { acc0[j] = 0.f; acc1[j] = 0.f; }

    for (int ck = 0; ck < 16; ++ck) {
        // ---- stage 8 channels into registers ----
        float4 v[8];
        float2 g[8];
#pragma unroll
        for (int cc = 0; cc < 8; ++cc) {
            const size_t co = (size_t)(ck * 8 + cc) * HW_;
            g[cc] = *(const float2*)(f0p + co);
            float4 t = make_float4(0.f, 0.f, 0.f, 0.f);
            if (qok) t = *(const float4*)(f1p + co);
            v[cc] = t;
        }
        __syncthreads();                 // WAR: previous chunk's reads complete
        if (q < 34) {
#pragma unroll
            for (int cc = 0; cc < 8; ++cc)
                *(float4*)&lds[cc][q * 4] = v[cc];
        }
        __syncthreads();                 // RAW: writes visible to all lanes

        // ---- consume: 18 FMA per channel per lane (2 pixels x 9 taps) ----
#pragma unroll
        for (int cc = 0; cc < 8; ++cc) {
            const float2* row = (const float2*)(&lds[cc][0]) + lane;
            const float2 w0 = row[0], w1 = row[1], w2 = row[2],
                         w3 = row[3], w4 = row[4];
            const float vv[10] = {w0.x, w0.y, w1.x, w1.y, w2.x,
                                  w2.y, w3.x, w3.y, w4.x, w4.y};
#pragma unroll
            for (int dx = 0; dx < 9; ++dx) {
                acc0[dx] += g[cc].x * vv[dx];
                acc1[dx] += g[cc].y * vv[dx + 1];
            }
        }
    }

    // disjoint k-slice writeout; OOB-row waves naturally wrote acc==0
    float* cb = corr + ((size_t)b * HW_ + (size_t)y0 * W_ + 2 * lane) * K_ + dg * 9;
#pragma unroll
    for (int j = 0; j < 9; ++j) cb[j] = acc0[j];
#pragma unroll
    for (int j = 0; j < 9; ++j) cb[K_ + j] = acc1[j];
}

// Kernel 2: scale by 1/sqrt(128), softmax over K in-place, prob + flow.
__global__ __launch_bounds__(256) void softmax_kernel(float* __restrict__ out) {
    const int t = threadIdx.x;
    const int wave = t >> 6, lane = t & 63;
    const int px = (blockIdx.x << 2) + wave;      // 0 .. 24575
    const int b = px / HW_;
    const int pl = px - b * HW_;
    const int y = pl >> 7, x = pl & 127;

    float* corr = out + FLOW_ELEMS + (size_t)px * K_;
    const float scale = 0.08838834764831845f;     // 1/sqrt(128)

    const bool has1 = lane < (K_ - 64);           // lane < 17
    float v0 = corr[lane] * scale;
    float v1 = has1 ? corr[lane + 64] * scale : -1e30f;

    float m = fmaxf(v0, v1);
#pragma unroll
    for (int off = 32; off; off >>= 1) m = fmaxf(m, __shfl_xor(m, off));

    float e0 = __expf(v0 - m);
    float e1 = has1 ? __expf(v1 - m) : 0.f;
    float s = e0 + e1;
#pragma unroll
    for (int off = 32; off; off >>= 1) s += __shfl_xor(s, off);

    const float inv = 1.f / s;
    const float p0 = e0 * inv;
    const float p1 = e1 * inv;

    corr[lane] = p0;
    if (has1) corr[lane + 64] = p1;

    float fx = p0 * (float)(lane % 9 - 4) + p1 * (float)((lane + 64) % 9 - 4);
    float fy = p0 * (float)(lane / 9 - 4) + p1 * (float)((lane + 64) / 9 - 4);
#pragma unroll
    for (int off = 32; off; off >>= 1) {
        fx += __shfl_xor(fx, off);
        fy += __shfl_xor(fy, off);
    }

    if (lane == 0) {
        out[((size_t)(b * 2 + 0) * H_ + y) * W_ + x] = fx;
        out[((size_t)(b * 2 + 1) * H_ + y) * W_ + x] = fy;
    }
}

extern "C" void kernel_launch(void* const* d_in, const int* in_sizes, int n_in,
                              void* d_out, int out_size, void* d_ws, size_t ws_size,
                              hipStream_t stream) {
    (void)in_sizes; (void)n_in; (void)d_ws; (void)ws_size; (void)out_size;
    const float* f0 = (const float*)d_in[0];
    const float* f1 = (const float*)d_in[1];
    float* out = (float*)d_out;

    corr_kernel<<<1728, 64, 0, stream>>>(f0, f1, out + FLOW_ELEMS);
    softmax_kernel<<<6144, 256, 0, stream>>>(out);
}